// Round 6
// baseline (110.807 us; speedup 1.0000x reference)
//
#include <hip/hip_runtime.h>
#include <math.h>

// Problem constants (from reference)
#define Bdim 32
#define Ndim 325
#define Kdim 20
#define Sdim 12      // S_IN == S_OUT == 12
#define Cdim 10
#define Hdim 48      // 4*S_OUT
#define NB   (Bdim*Ndim)                  // 10400 (b,n) pairs
#define OUT_SCALARS (NB*Cdim*Sdim)        // output_data floats, then 3 scalars
#define Tpairs (Kdim*(Kdim-1)/2)          // 190 upper-triangle pairs
#define BN_BLOCKS (NB/4)                  // 2600 bn blocks (4 bn each)

// Workspace layout (float offsets); all blocks 16B-aligned
#define O_WH  0                           // NB*12 node features wh
#define O_HX  (O_WH + NB*Sdim)            // NB*48: hx + a1_b (bias pre-folded)
#define O_HY  (O_HX + NB*Hdim)            // NB*48: hy
#define O_PCL (O_HY + NB*Hdim)            // BN_BLOCKS per-block cluster-loss partials
#define O_PDS (O_PCL + BN_BLOCKS)         // BN_BLOCKS per-block dist-sum partials
#define O_PWH (O_PDS + BN_BLOCKS)         // NB per-node wh-sum partials
#define O_ATT (O_PWH + NB)                // NB*K*12 softmaxed probs (c padded to 12)
#define WS_BASE_FLOATS (O_ATT + NB*Kdim*12)

__device__ __forceinline__ float leaky(float x) { return x >= 0.f ? x : 0.5f * x; }

// ---------------------------------------------------------------------------
// K1: per-node wh, hx(+b1), hy + wh-sum partial.  4 nodes per 256-thread block
// ---------------------------------------------------------------------------
__global__ __launch_bounds__(256)
void node_kernel(const float* __restrict__ x,
                 const float* __restrict__ wW, const float* __restrict__ wb,
                 const float* __restrict__ A1, const float* __restrict__ b1,
                 float* __restrict__ ws)
{
    __shared__ float s_wh[4][Sdim];
    const int slot = threadIdx.x >> 6, lane = threadIdx.x & 63;
    const int node = blockIdx.x * 4 + slot;
    const float* xr = x + (size_t)node * Sdim;

    float v = 0.f;
    if (lane < Sdim) {
        float acc = wb[lane];
        #pragma unroll
        for (int i = 0; i < Sdim; i++) acc += xr[i] * wW[i * Sdim + lane];
        v = leaky(acc);
        s_wh[slot][lane] = v;
        ws[O_WH + (size_t)node * Sdim + lane] = v;
    }
    __syncthreads();

    #pragma unroll
    for (int rep = 0; rep < 2; rep++) {
        const int e = lane + rep * 64;
        if (e < 2 * Hdim) {
            const int which = e / Hdim, d = e - which * Hdim;
            float acc = which ? 0.f : b1[d];          // fold a1_b into hx
            #pragma unroll
            for (int s = 0; s < Sdim; s++)
                acc += s_wh[slot][s] * A1[(which * Sdim + s) * Hdim + d];
            ws[(which ? O_HY : O_HX) + (size_t)node * Hdim + d] = acc;
        }
    }

    #pragma unroll
    for (int off = 32; off > 0; off >>= 1) v += __shfl_down(v, off);
    if (lane == 0) ws[O_PWH + node] = v;
}

// ---------------------------------------------------------------------------
// K2: attention probs, one thread per (bn,k) edge. A2/b2 accessed with
// wave-uniform unrolled indices -> scalar cache (s_load), ZERO LDS traffic.
// Softmax fused in-thread; writes 12 floats (10 probs + 2 zero pad).
// ---------------------------------------------------------------------------
__global__ __launch_bounds__(256)
void att_kernel(const int* __restrict__ topk,
                const float* __restrict__ A2, const float* __restrict__ b2,
                float* __restrict__ ws)
{
    const int gid = blockIdx.x * 256 + threadIdx.x;
    if (gid >= NB * Kdim) return;
    const int bn = gid / Kdim;
    const int b  = bn / Ndim;
    const int j  = topk[gid];

    const float4* hx4 = (const float4*)(ws + O_HX + (size_t)bn * Hdim);
    const float4* hy4 = (const float4*)(ws + O_HY + ((size_t)b * Ndim + j) * Hdim);

    float acc[Cdim];
    #pragma unroll
    for (int c = 0; c < Cdim; c++) acc[c] = b2[c];
    #pragma unroll
    for (int q = 0; q < 12; q++) {
        const float4 xv = hx4[q], yv = hy4[q];
        const float hh[4] = { leaky(xv.x + yv.x), leaky(xv.y + yv.y),
                              leaky(xv.z + yv.z), leaky(xv.w + yv.w) };
        #pragma unroll
        for (int i = 0; i < 4; i++) {
            #pragma unroll
            for (int c = 0; c < Cdim; c++)
                acc[c] += hh[i] * A2[(q * 4 + i) * Cdim + c];
        }
    }
    float m = -1e30f;
    #pragma unroll
    for (int c = 0; c < Cdim; c++) { acc[c] = leaky(acc[c]); m = fmaxf(m, acc[c]); }
    float sum = 0.f;
    #pragma unroll
    for (int c = 0; c < Cdim; c++) { acc[c] = __expf(acc[c] - m); sum += acc[c]; }
    const float inv = 1.f / sum;

    float* ar = ws + O_ATT + (size_t)gid * 12;
    *(float4*)(ar + 0) = make_float4(acc[0]*inv, acc[1]*inv, acc[2]*inv, acc[3]*inv);
    *(float4*)(ar + 4) = make_float4(acc[4]*inv, acc[5]*inv, acc[6]*inv, acc[7]*inv);
    *(float4*)(ar + 8) = make_float4(acc[8]*inv, acc[9]*inv, 0.f, 0.f);
}

// ---------------------------------------------------------------------------
// K3: 4 bn per 256-thread block (1 wave each). Stage whj + probs, then
// norm (lanes 0..19) || einsum (lanes 20..49), then 190-pair symmetric loss
// using dot(whj)*invn_k*invn_l (wtn never materialized). Block partials only.
// ---------------------------------------------------------------------------
__global__ __launch_bounds__(256)
void bn_kernel(const int* __restrict__ topk,
               float* __restrict__ ws, float* __restrict__ out)
{
    __shared__ float s_whj [4][Kdim][12];   // 48B rows, float4-aligned
    __shared__ float s_am  [4][Kdim][12];   // probs, c padded with zeros
    __shared__ float s_invn[4][Kdim];
    __shared__ int   s_idx [4][Kdim];
    __shared__ float s_red[2][4];

    const int tid = threadIdx.x;
    const int slot = tid >> 6, t = tid & 63;
    const int bn = blockIdx.x * 4 + slot, b = bn / Ndim;

    if (t < Kdim) s_idx[slot][t] = topk[(size_t)bn * Kdim + t];
    __syncthreads();

    // stage: lane t<60 handles float4 #t of both whj (gathered) and am (coalesced)
    if (t < 60) {
        const int k = t / 3, q = t - k * 3;
        const float4 v = *(const float4*)(ws + O_WH + ((size_t)b * Ndim + s_idx[slot][k]) * Sdim + q * 4);
        *(float4*)&s_whj[slot][k][q * 4] = v;
        const float4 a = *(const float4*)(ws + O_ATT + (size_t)bn * (Kdim * 12) + t * 4);
        *(float4*)&s_am[slot][k][q * 4] = a;
    }
    __syncthreads();

    float cl = 0.f, ds = 0.f;

    if (t < Kdim) {
        // per-k norm factor + diagonal dist contribution
        const float4 w0 = *(const float4*)&s_whj[slot][t][0];
        const float4 w1 = *(const float4*)&s_whj[slot][t][4];
        const float4 w2 = *(const float4*)&s_whj[slot][t][8];
        const float nn = w0.x*w0.x + w0.y*w0.y + w0.z*w0.z + w0.w*w0.w
                       + w1.x*w1.x + w1.y*w1.y + w1.z*w1.z + w1.w*w1.w
                       + w2.x*w2.x + w2.y*w2.y + w2.z*w2.z + w2.w*w2.w;
        const float invn = 1.f / (sqrtf(nn) + 1e-8f);
        s_invn[slot][t] = invn;
        ds += nn * invn * invn;               // dist_mat diagonal term
    } else if (t < Kdim + 30) {
        // output einsum: lane = (c, s-quad), float4 stores
        const int e = t - Kdim, c = e / 3, sq = e - c * 3;
        float4 o = make_float4(0.f, 0.f, 0.f, 0.f);
        #pragma unroll
        for (int k = 0; k < Kdim; k++) {
            const float a = s_am[slot][k][c];
            const float4 w = *(const float4*)&s_whj[slot][k][sq * 4];
            o.x += a * w.x; o.y += a * w.y; o.z += a * w.z; o.w += a * w.w;
        }
        *(float4*)(out + (size_t)bn * (Cdim * Sdim) + c * Sdim + sq * 4) = o;
    }
    __syncthreads();

    // loss: 190 upper-triangle pairs, doubled (dist/prob are symmetric)
    #pragma unroll
    for (int it = 0; it < 3; it++) {
        const int e = t + it * 64;
        if (e < Tpairs) {
            const int r = Tpairs - 1 - e;
            const int m = (int)((sqrtf((float)(8 * r + 1)) - 1.f) * 0.5f + 1e-4f);
            const int k = Kdim - 2 - m;
            const int l = Kdim - 1 - (r - (m * (m + 1)) / 2);

            const float4 a0 = *(const float4*)&s_whj[slot][k][0];
            const float4 a1 = *(const float4*)&s_whj[slot][k][4];
            const float4 a2 = *(const float4*)&s_whj[slot][k][8];
            const float4 c0 = *(const float4*)&s_whj[slot][l][0];
            const float4 c1 = *(const float4*)&s_whj[slot][l][4];
            const float4 c2 = *(const float4*)&s_whj[slot][l][8];
            const float draw = a0.x*c0.x + a0.y*c0.y + a0.z*c0.z + a0.w*c0.w
                             + a1.x*c1.x + a1.y*c1.y + a1.z*c1.z + a1.w*c1.w
                             + a2.x*c2.x + a2.y*c2.y + a2.z*c2.z + a2.w*c2.w;
            const float d = draw * s_invn[slot][k] * s_invn[slot][l];

            const float4 p0 = *(const float4*)&s_am[slot][k][0];
            const float4 p1 = *(const float4*)&s_am[slot][k][4];
            const float4 p2 = *(const float4*)&s_am[slot][k][8];
            const float4 q0 = *(const float4*)&s_am[slot][l][0];
            const float4 q1 = *(const float4*)&s_am[slot][l][4];
            const float4 q2 = *(const float4*)&s_am[slot][l][8];
            float p = p0.x*q0.x + p0.y*q0.y + p0.z*q0.z + p0.w*q0.w
                    + p1.x*q1.x + p1.y*q1.y + p1.z*q1.z + p1.w*q1.w
                    + p2.x*q2.x + p2.y*q2.y + p2.z*q2.z + p2.w*q2.w;

            p = fminf(fmaxf(p, 1e-4f), 1.f - 1e-4f);
            const float lp = __logf(p);
            ds += 2.f * d;
            cl += 2.f * ((d >= 0.5f) ? -lp : lp);
        }
    }

    // wave reduce, then cross-slot reduce -> one block partial (plain stores)
    #pragma unroll
    for (int off = 32; off > 0; off >>= 1) {
        cl += __shfl_down(cl, off);
        ds += __shfl_down(ds, off);
    }
    if (t == 0) { s_red[0][slot] = cl; s_red[1][slot] = ds; }
    __syncthreads();
    if (tid == 0) {
        ws[O_PCL + blockIdx.x] = s_red[0][0] + s_red[0][1] + s_red[0][2] + s_red[0][3];
        ws[O_PDS + blockIdx.x] = s_red[1][0] + s_red[1][1] + s_red[1][2] + s_red[1][3];
    }
}

// ---------------------------------------------------------------------------
// K4: reduce partials -> 3 output scalars (tiny)
// ---------------------------------------------------------------------------
__global__ __launch_bounds__(1024)
void finalize(const float* __restrict__ ws, float* __restrict__ out)
{
    const int t = threadIdx.x;
    float cl = 0.f, ds = 0.f, wm = 0.f;
    for (int i = t; i < BN_BLOCKS; i += 1024) {
        cl += ws[O_PCL + i]; ds += ws[O_PDS + i];
    }
    for (int i = t; i < NB; i += 1024) wm += ws[O_PWH + i];
    #pragma unroll
    for (int off = 32; off > 0; off >>= 1) {
        cl += __shfl_down(cl, off);
        ds += __shfl_down(ds, off);
        wm += __shfl_down(wm, off);
    }
    __shared__ float r[3][16];
    const int w = t >> 6, lane = t & 63;
    if (lane == 0) { r[0][w] = cl; r[1][w] = ds; r[2][w] = wm; }
    __syncthreads();
    if (t == 0) {
        float c = 0.f, d = 0.f, m = 0.f;
        #pragma unroll
        for (int i = 0; i < 16; i++) { c += r[0][i]; d += r[1][i]; m += r[2][i]; }
        out[OUT_SCALARS + 0] = c * (1.f / (float)NB);
        out[OUT_SCALARS + 1] = d * (1.f / ((float)NB * Kdim * Kdim));
        out[OUT_SCALARS + 2] = m * (1.f / ((float)NB * Sdim));
    }
}

// ---------------------------------------------------------------------------
// Fallback: round-1 monolithic kernel (used only if ws is too small)
// ---------------------------------------------------------------------------
__global__ void zero_scalars(float* out) {
    const int t = threadIdx.x;
    if (t < 3) out[OUT_SCALARS + t] = 0.f;
}

__global__ __launch_bounds__(64)
void fused_kernel(const float* __restrict__ input_data,
                  const float* __restrict__ w_W,  const float* __restrict__ w_b,
                  const float* __restrict__ a1_W, const float* __restrict__ a1_b,
                  const float* __restrict__ a2_W, const float* __restrict__ a2_b,
                  const int*   __restrict__ topk,
                  float* __restrict__ out)
{
    __shared__ float s_wW[Sdim * Sdim];
    __shared__ float s_wb[Sdim];
    __shared__ float s_A1[2 * Sdim * Hdim];
    __shared__ float s_b1[Hdim];
    __shared__ float s_A2f[Hdim * Cdim];
    __shared__ float s_b2f[Cdim];
    __shared__ float s_whs[Sdim];
    __shared__ float s_hx[Hdim];
    __shared__ float s_whj[Kdim][Sdim + 1];
    __shared__ float s_hid[Kdim][Hdim + 1];
    __shared__ float s_am [Kdim][Cdim + 1];
    __shared__ float s_wtn[Kdim][Sdim + 1];
    __shared__ int   s_idx[Kdim];

    const int t = threadIdx.x, bn = blockIdx.x, b = bn / Ndim;

    for (int i = t; i < Sdim * Sdim; i += 64)      s_wW[i] = w_W[i];
    if (t < Sdim)                                  s_wb[t] = w_b[t];
    for (int i = t; i < 2 * Sdim * Hdim; i += 64)  s_A1[i] = a1_W[i];
    if (t < Hdim)                                  s_b1[t] = a1_b[t];
    for (int i = t; i < Hdim * Cdim; i += 64)      s_A2f[i] = a2_W[i];
    if (t < Cdim)                                  s_b2f[t] = a2_b[t];
    if (t < Kdim)                                  s_idx[t] = topk[(size_t)bn * Kdim + t];
    __syncthreads();

    const float* xs = input_data + (size_t)bn * Sdim;
    if (t < Sdim) {
        float acc = s_wb[t];
        #pragma unroll
        for (int i = 0; i < Sdim; i++) acc += xs[i] * s_wW[i * Sdim + t];
        s_whs[t] = leaky(acc);
    }
    __syncthreads();

    if (t < Hdim) {
        float acc = 0.f;
        #pragma unroll
        for (int s = 0; s < Sdim; s++) acc += s_whs[s] * s_A1[s * Hdim + t];
        s_hx[t] = acc;
    }
    for (int e = t; e < Kdim * Sdim; e += 64) {
        const int k = e / Sdim, ss = e - k * Sdim;
        const float* xj = input_data + ((size_t)b * Ndim + s_idx[k]) * Sdim;
        float acc = s_wb[ss];
        #pragma unroll
        for (int i = 0; i < Sdim; i++) acc += xj[i] * s_wW[i * Sdim + ss];
        s_whj[k][ss] = leaky(acc);
    }
    __syncthreads();

    for (int e = t; e < Kdim * Hdim; e += 64) {
        const int k = e / Hdim, d = e - k * Hdim;
        float acc = s_hx[d] + s_b1[d];
        #pragma unroll
        for (int s = 0; s < Sdim; s++) acc += s_whj[k][s] * s_A1[(Sdim + s) * Hdim + d];
        s_hid[k][d] = leaky(acc);
    }
    __syncthreads();

    for (int e = t; e < Kdim * Cdim; e += 64) {
        const int k = e / Cdim, c = e - k * Cdim;
        float acc = s_b2f[c];
        #pragma unroll
        for (int d = 0; d < Hdim; d++) acc += s_hid[k][d] * s_A2f[d * Cdim + c];
        s_am[k][c] = leaky(acc);
    }
    __syncthreads();

    if (t < Kdim) {
        float m = -1e30f;
        #pragma unroll
        for (int c = 0; c < Cdim; c++) m = fmaxf(m, s_am[t][c]);
        float ex[Cdim]; float sum = 0.f;
        #pragma unroll
        for (int c = 0; c < Cdim; c++) { ex[c] = expf(s_am[t][c] - m); sum += ex[c]; }
        const float inv = 1.f / sum;
        #pragma unroll
        for (int c = 0; c < Cdim; c++) s_am[t][c] = ex[c] * inv;
        float nn = 0.f;
        #pragma unroll
        for (int s = 0; s < Sdim; s++) nn += s_whj[t][s] * s_whj[t][s];
        const float invn = 1.f / (sqrtf(nn) + 1e-8f);
        #pragma unroll
        for (int s = 0; s < Sdim; s++) s_wtn[t][s] = s_whj[t][s] * invn;
    }
    __syncthreads();

    float* op = out + (size_t)bn * (Cdim * Sdim);
    for (int e = t; e < Cdim * Sdim; e += 64) {
        const int c = e / Sdim, ss = e - c * Sdim;
        float acc = 0.f;
        #pragma unroll
        for (int k = 0; k < Kdim; k++) acc += s_am[k][c] * s_whj[k][ss];
        op[e] = acc;
    }

    float cl = 0.f, ds = 0.f;
    for (int e = t; e < Kdim * Kdim; e += 64) {
        const int k = e / Kdim, l = e - k * Kdim;
        float d = 0.f;
        #pragma unroll
        for (int s = 0; s < Sdim; s++) d += s_wtn[k][s] * s_wtn[l][s];
        ds += d;
        if (k != l) {
            float p = 0.f;
            #pragma unroll
            for (int c = 0; c < Cdim; c++) p += s_am[k][c] * s_am[l][c];
            p = fminf(fmaxf(p, 1e-4f), 1.f - 1e-4f);
            const float lp = logf(p);
            cl += (d >= 0.5f) ? -lp : lp;
        }
    }
    float whl = (t < Sdim) ? s_whs[t] : 0.f;
    #pragma unroll
    for (int off = 32; off > 0; off >>= 1) {
        cl  += __shfl_down(cl,  off);
        ds  += __shfl_down(ds,  off);
        whl += __shfl_down(whl, off);
    }
    if (t == 0) {
        atomicAdd(&out[OUT_SCALARS + 0], cl  * (1.f / (float)NB));
        atomicAdd(&out[OUT_SCALARS + 1], ds  * (1.f / ((float)NB * Kdim * Kdim)));
        atomicAdd(&out[OUT_SCALARS + 2], whl * (1.f / ((float)NB * Sdim)));
    }
}

extern "C" void kernel_launch(void* const* d_in, const int* in_sizes, int n_in,
                              void* d_out, int out_size, void* d_ws, size_t ws_size,
                              hipStream_t stream) {
    (void)in_sizes; (void)n_in; (void)out_size;
    // 0=fushed_features(unused), 1=input_data, 2=w_W, 3=w_b, 4=a1_W, 5=a1_b,
    // 6=a2_W, 7=a2_b, 8=adj_mx_topk_index
    const float* input_data = (const float*)d_in[1];
    const float* w_W  = (const float*)d_in[2];
    const float* w_b  = (const float*)d_in[3];
    const float* a1_W = (const float*)d_in[4];
    const float* a1_b = (const float*)d_in[5];
    const float* a2_W = (const float*)d_in[6];
    const float* a2_b = (const float*)d_in[7];
    const int*   topk = (const int*)d_in[8];
    float* out = (float*)d_out;
    float* ws  = (float*)d_ws;

    if (ws_size >= (size_t)WS_BASE_FLOATS * sizeof(float)) {
        hipLaunchKernelGGL(node_kernel, dim3(NB / 4), dim3(256), 0, stream,
                           input_data, w_W, w_b, a1_W, a1_b, ws);
        hipLaunchKernelGGL(att_kernel, dim3((NB * Kdim + 255) / 256), dim3(256), 0, stream,
                           topk, a2_W, a2_b, ws);
        hipLaunchKernelGGL(bn_kernel, dim3(BN_BLOCKS), dim3(256), 0, stream,
                           topk, ws, out);
        hipLaunchKernelGGL(finalize, dim3(1), dim3(1024), 0, stream, ws, out);
    } else {
        hipLaunchKernelGGL(zero_scalars, dim3(1), dim3(64), 0, stream, out);
        hipLaunchKernelGGL(fused_kernel, dim3(NB), dim3(64), 0, stream,
                           input_data, w_W, w_b, a1_W, a1_b, a2_W, a2_b, topk, out);
    }
}

// Round 7
// 109.804 us; speedup vs baseline: 1.0091x; 1.0091x over previous
//
#include <hip/hip_runtime.h>
#include <math.h>

// Problem constants (from reference)
#define Bdim 32
#define Ndim 325
#define Kdim 20
#define Sdim 12      // S_IN == S_OUT == 12
#define Cdim 10
#define Hdim 48      // 4*S_OUT
#define NB   (Bdim*Ndim)                  // 10400 (b,n) pairs
#define OUT_SCALARS (NB*Cdim*Sdim)        // output_data floats, then 3 scalars
#define Tpairs (Kdim*(Kdim-1)/2)          // 190 upper-triangle pairs
#define BN_BLOCKS (NB/4)                  // 2600 bn blocks (4 bn each)
#define NODE_BLOCKS 260                   // 40 nodes per block
#define NPB 40

// Workspace layout (float offsets); all blocks 16B-aligned
#define O_WH  0                           // NB*12 node features wh
#define O_HX  (O_WH + NB*Sdim)            // NB*48: hx + a1_b (bias pre-folded)
#define O_HY  (O_HX + NB*Hdim)            // NB*48: hy
#define O_PCL (O_HY + NB*Hdim)            // BN_BLOCKS cluster-loss partials
#define O_PDS (O_PCL + BN_BLOCKS)         // BN_BLOCKS dist-sum partials
#define O_PWH (O_PDS + BN_BLOCKS)         // NODE_BLOCKS wh-sum partials
#define O_ATT (O_PWH + NODE_BLOCKS)       // NB*K*12 softmaxed probs (c padded to 12)
#define WS_BASE_FLOATS (O_ATT + NB*Kdim*12)

__device__ __forceinline__ float leaky(float x) { return x >= 0.f ? x : 0.5f * x; }

// ---------------------------------------------------------------------------
// K1: grid-stride node kernel. 260 blocks x 256; 40 nodes per block.
// wh -> LDS + ws; hx(+b1), hy -> ws; per-BLOCK wh-sum partial.
// ---------------------------------------------------------------------------
__global__ __launch_bounds__(256)
void node_kernel(const float* __restrict__ x,
                 const float* __restrict__ wW, const float* __restrict__ wb,
                 const float* __restrict__ A1, const float* __restrict__ b1,
                 float* __restrict__ ws)
{
    __shared__ float s_wh[NPB][Sdim];
    __shared__ float s_r[4];
    const int tid = threadIdx.x;
    const int base = blockIdx.x * NPB;

    float v = 0.f;  // wh partial
    // wh: 40*12 = 480 elems
    #pragma unroll
    for (int rep = 0; rep < 2; rep++) {
        const int e = tid + rep * 256;
        if (e < NPB * Sdim) {
            const int n = e / Sdim, s = e - n * Sdim;
            const float* xr = x + (size_t)(base + n) * Sdim;
            float acc = wb[s];
            #pragma unroll
            for (int i = 0; i < Sdim; i++) acc += xr[i] * wW[i * Sdim + s];
            acc = leaky(acc);
            s_wh[n][s] = acc;
            ws[O_WH + (size_t)(base + n) * Sdim + s] = acc;
            v += acc;
        }
    }
    __syncthreads();

    // hx/hy: 40*96 = 3840 elems
    #pragma unroll
    for (int rep = 0; rep < 15; rep++) {
        const int e = tid + rep * 256;
        const int n = e / 96, r = e - n * 96;
        const int which = r / Hdim, d = r - which * Hdim;
        const float4 w0 = *(const float4*)&s_wh[n][0];
        const float4 w1 = *(const float4*)&s_wh[n][4];
        const float4 w2 = *(const float4*)&s_wh[n][8];
        const float* Ac = A1 + (which * Sdim) * Hdim + d;  // stride Hdim over s
        float acc = which ? 0.f : b1[d];                   // fold a1_b into hx
        acc += w0.x*Ac[0*Hdim] + w0.y*Ac[1*Hdim] + w0.z*Ac[2*Hdim] + w0.w*Ac[3*Hdim]
             + w1.x*Ac[4*Hdim] + w1.y*Ac[5*Hdim] + w1.z*Ac[6*Hdim] + w1.w*Ac[7*Hdim]
             + w2.x*Ac[8*Hdim] + w2.y*Ac[9*Hdim] + w2.z*Ac[10*Hdim] + w2.w*Ac[11*Hdim];
        ws[(which ? O_HY : O_HX) + (size_t)(base + n) * Hdim + d] = acc;
    }

    // block-reduce wh partial
    #pragma unroll
    for (int off = 32; off > 0; off >>= 1) v += __shfl_down(v, off);
    if ((tid & 63) == 0) s_r[tid >> 6] = v;
    __syncthreads();
    if (tid == 0) ws[O_PWH + blockIdx.x] = s_r[0] + s_r[1] + s_r[2] + s_r[3];
}

// ---------------------------------------------------------------------------
// K2: attention probs, one thread per (bn,k) edge. A2/b2 accessed with
// wave-uniform unrolled indices -> scalar cache (s_load), ZERO LDS traffic.
// Softmax fused in-thread; writes 12 floats (10 probs + 2 zero pad).
// ---------------------------------------------------------------------------
__global__ __launch_bounds__(256)
void att_kernel(const int* __restrict__ topk,
                const float* __restrict__ A2, const float* __restrict__ b2,
                float* __restrict__ ws)
{
    const int gid = blockIdx.x * 256 + threadIdx.x;
    if (gid >= NB * Kdim) return;
    const int bn = gid / Kdim;
    const int b  = bn / Ndim;
    const int j  = topk[gid];

    const float4* hx4 = (const float4*)(ws + O_HX + (size_t)bn * Hdim);
    const float4* hy4 = (const float4*)(ws + O_HY + ((size_t)b * Ndim + j) * Hdim);

    float acc[Cdim];
    #pragma unroll
    for (int c = 0; c < Cdim; c++) acc[c] = b2[c];
    #pragma unroll
    for (int q = 0; q < 12; q++) {
        const float4 xv = hx4[q], yv = hy4[q];
        const float hh[4] = { leaky(xv.x + yv.x), leaky(xv.y + yv.y),
                              leaky(xv.z + yv.z), leaky(xv.w + yv.w) };
        #pragma unroll
        for (int i = 0; i < 4; i++) {
            #pragma unroll
            for (int c = 0; c < Cdim; c++)
                acc[c] += hh[i] * A2[(q * 4 + i) * Cdim + c];
        }
    }
    float m = -1e30f;
    #pragma unroll
    for (int c = 0; c < Cdim; c++) { acc[c] = leaky(acc[c]); m = fmaxf(m, acc[c]); }
    float sum = 0.f;
    #pragma unroll
    for (int c = 0; c < Cdim; c++) { acc[c] = __expf(acc[c] - m); sum += acc[c]; }
    const float inv = 1.f / sum;

    float* ar = ws + O_ATT + (size_t)gid * 12;
    *(float4*)(ar + 0) = make_float4(acc[0]*inv, acc[1]*inv, acc[2]*inv, acc[3]*inv);
    *(float4*)(ar + 4) = make_float4(acc[4]*inv, acc[5]*inv, acc[6]*inv, acc[7]*inv);
    *(float4*)(ar + 8) = make_float4(acc[8]*inv, acc[9]*inv, 0.f, 0.f);
}

// ---------------------------------------------------------------------------
// K3: 4 bn per 256-thread block (1 wave each). WAVE-SYNCHRONOUS: all
// producer->consumer edges are intra-wave, so NO __syncthreads until the
// final cross-slot reduce (removes the all-wave vmcnt(0) barrier drains).
// ---------------------------------------------------------------------------
__global__ __launch_bounds__(256)
void bn_kernel(const int* __restrict__ topk,
               float* __restrict__ ws, float* __restrict__ out)
{
    __shared__ float s_whj [4][Kdim][12];   // 48B rows, float4-aligned
    __shared__ float s_am  [4][Kdim][12];   // probs, c padded with zeros
    __shared__ float s_invn[4][Kdim];
    __shared__ int   s_idx [4][Kdim];
    __shared__ float s_red[2][4];

    const int tid = threadIdx.x;
    const int slot = tid >> 6, t = tid & 63;
    const int bn = blockIdx.x * 4 + slot, b = bn / Ndim;

    if (t < Kdim) s_idx[slot][t] = topk[(size_t)bn * Kdim + t];
    __builtin_amdgcn_wave_barrier();        // intra-wave ordering only

    // stage: lane t<60 handles float4 #t of both whj (gathered) and am (coalesced)
    if (t < 60) {
        const int k = t / 3, q = t - k * 3;
        const float4 v = *(const float4*)(ws + O_WH + ((size_t)b * Ndim + s_idx[slot][k]) * Sdim + q * 4);
        *(float4*)&s_whj[slot][k][q * 4] = v;
        const float4 a = *(const float4*)(ws + O_ATT + (size_t)bn * (Kdim * 12) + t * 4);
        *(float4*)&s_am[slot][k][q * 4] = a;
    }
    __builtin_amdgcn_wave_barrier();

    float cl = 0.f, ds = 0.f;

    if (t < Kdim) {
        // per-k norm factor + diagonal dist contribution
        const float4 w0 = *(const float4*)&s_whj[slot][t][0];
        const float4 w1 = *(const float4*)&s_whj[slot][t][4];
        const float4 w2 = *(const float4*)&s_whj[slot][t][8];
        const float nn = w0.x*w0.x + w0.y*w0.y + w0.z*w0.z + w0.w*w0.w
                       + w1.x*w1.x + w1.y*w1.y + w1.z*w1.z + w1.w*w1.w
                       + w2.x*w2.x + w2.y*w2.y + w2.z*w2.z + w2.w*w2.w;
        const float invn = 1.f / (sqrtf(nn) + 1e-8f);
        s_invn[slot][t] = invn;
        ds += nn * invn * invn;               // dist_mat diagonal term
    } else if (t < Kdim + 30) {
        // output einsum: lane = (c, s-quad), float4 stores
        const int e = t - Kdim, c = e / 3, sq = e - c * 3;
        float4 o = make_float4(0.f, 0.f, 0.f, 0.f);
        #pragma unroll
        for (int k = 0; k < Kdim; k++) {
            const float a = s_am[slot][k][c];
            const float4 w = *(const float4*)&s_whj[slot][k][sq * 4];
            o.x += a * w.x; o.y += a * w.y; o.z += a * w.z; o.w += a * w.w;
        }
        *(float4*)(out + (size_t)bn * (Cdim * Sdim) + c * Sdim + sq * 4) = o;
    }
    __builtin_amdgcn_wave_barrier();

    // loss: 190 upper-triangle pairs, doubled (dist/prob are symmetric)
    #pragma unroll
    for (int it = 0; it < 3; it++) {
        const int e = t + it * 64;
        if (e < Tpairs) {
            const int r = Tpairs - 1 - e;
            const int m = (int)((sqrtf((float)(8 * r + 1)) - 1.f) * 0.5f + 1e-4f);
            const int k = Kdim - 2 - m;
            const int l = Kdim - 1 - (r - (m * (m + 1)) / 2);

            const float4 a0 = *(const float4*)&s_whj[slot][k][0];
            const float4 a1 = *(const float4*)&s_whj[slot][k][4];
            const float4 a2 = *(const float4*)&s_whj[slot][k][8];
            const float4 c0 = *(const float4*)&s_whj[slot][l][0];
            const float4 c1 = *(const float4*)&s_whj[slot][l][4];
            const float4 c2 = *(const float4*)&s_whj[slot][l][8];
            const float draw = a0.x*c0.x + a0.y*c0.y + a0.z*c0.z + a0.w*c0.w
                             + a1.x*c1.x + a1.y*c1.y + a1.z*c1.z + a1.w*c1.w
                             + a2.x*c2.x + a2.y*c2.y + a2.z*c2.z + a2.w*c2.w;
            const float d = draw * s_invn[slot][k] * s_invn[slot][l];

            const float4 p0 = *(const float4*)&s_am[slot][k][0];
            const float4 p1 = *(const float4*)&s_am[slot][k][4];
            const float4 p2 = *(const float4*)&s_am[slot][k][8];
            const float4 q0 = *(const float4*)&s_am[slot][l][0];
            const float4 q1 = *(const float4*)&s_am[slot][l][4];
            const float4 q2 = *(const float4*)&s_am[slot][l][8];
            float p = p0.x*q0.x + p0.y*q0.y + p0.z*q0.z + p0.w*q0.w
                    + p1.x*q1.x + p1.y*q1.y + p1.z*q1.z + p1.w*q1.w
                    + p2.x*q2.x + p2.y*q2.y + p2.z*q2.z + p2.w*q2.w;

            p = fminf(fmaxf(p, 1e-4f), 1.f - 1e-4f);
            const float lp = __logf(p);
            ds += 2.f * d;
            cl += 2.f * ((d >= 0.5f) ? -lp : lp);
        }
    }

    // wave reduce, then cross-slot reduce -> one block partial (plain stores)
    #pragma unroll
    for (int off = 32; off > 0; off >>= 1) {
        cl += __shfl_down(cl, off);
        ds += __shfl_down(ds, off);
    }
    if (t == 0) { s_red[0][slot] = cl; s_red[1][slot] = ds; }
    __syncthreads();                        // the ONLY block barrier
    if (tid == 0) {
        ws[O_PCL + blockIdx.x] = s_red[0][0] + s_red[0][1] + s_red[0][2] + s_red[0][3];
        ws[O_PDS + blockIdx.x] = s_red[1][0] + s_red[1][1] + s_red[1][2] + s_red[1][3];
    }
}

// ---------------------------------------------------------------------------
// K4: reduce partials -> 3 output scalars (tiny)
// ---------------------------------------------------------------------------
__global__ __launch_bounds__(1024)
void finalize(const float* __restrict__ ws, float* __restrict__ out)
{
    const int t = threadIdx.x;
    float cl = 0.f, ds = 0.f, wm = 0.f;
    for (int i = t; i < BN_BLOCKS; i += 1024) {
        cl += ws[O_PCL + i]; ds += ws[O_PDS + i];
    }
    if (t < NODE_BLOCKS) wm = ws[O_PWH + t];
    #pragma unroll
    for (int off = 32; off > 0; off >>= 1) {
        cl += __shfl_down(cl, off);
        ds += __shfl_down(ds, off);
        wm += __shfl_down(wm, off);
    }
    __shared__ float r[3][16];
    const int w = t >> 6, lane = t & 63;
    if (lane == 0) { r[0][w] = cl; r[1][w] = ds; r[2][w] = wm; }
    __syncthreads();
    if (t == 0) {
        float c = 0.f, d = 0.f, m = 0.f;
        #pragma unroll
        for (int i = 0; i < 16; i++) { c += r[0][i]; d += r[1][i]; m += r[2][i]; }
        out[OUT_SCALARS + 0] = c * (1.f / (float)NB);
        out[OUT_SCALARS + 1] = d * (1.f / ((float)NB * Kdim * Kdim));
        out[OUT_SCALARS + 2] = m * (1.f / ((float)NB * Sdim));
    }
}

// ---------------------------------------------------------------------------
// Fallback: round-1 monolithic kernel (used only if ws is too small)
// ---------------------------------------------------------------------------
__global__ void zero_scalars(float* out) {
    const int t = threadIdx.x;
    if (t < 3) out[OUT_SCALARS + t] = 0.f;
}

__global__ __launch_bounds__(64)
void fused_kernel(const float* __restrict__ input_data,
                  const float* __restrict__ w_W,  const float* __restrict__ w_b,
                  const float* __restrict__ a1_W, const float* __restrict__ a1_b,
                  const float* __restrict__ a2_W, const float* __restrict__ a2_b,
                  const int*   __restrict__ topk,
                  float* __restrict__ out)
{
    __shared__ float s_wW[Sdim * Sdim];
    __shared__ float s_wb[Sdim];
    __shared__ float s_A1[2 * Sdim * Hdim];
    __shared__ float s_b1[Hdim];
    __shared__ float s_A2f[Hdim * Cdim];
    __shared__ float s_b2f[Cdim];
    __shared__ float s_whs[Sdim];
    __shared__ float s_hx[Hdim];
    __shared__ float s_whj[Kdim][Sdim + 1];
    __shared__ float s_hid[Kdim][Hdim + 1];
    __shared__ float s_am [Kdim][Cdim + 1];
    __shared__ float s_wtn[Kdim][Sdim + 1];
    __shared__ int   s_idx[Kdim];

    const int t = threadIdx.x, bn = blockIdx.x, b = bn / Ndim;

    for (int i = t; i < Sdim * Sdim; i += 64)      s_wW[i] = w_W[i];
    if (t < Sdim)                                  s_wb[t] = w_b[t];
    for (int i = t; i < 2 * Sdim * Hdim; i += 64)  s_A1[i] = a1_W[i];
    if (t < Hdim)                                  s_b1[t] = a1_b[t];
    for (int i = t; i < Hdim * Cdim; i += 64)      s_A2f[i] = a2_W[i];
    if (t < Cdim)                                  s_b2f[t] = a2_b[t];
    if (t < Kdim)                                  s_idx[t] = topk[(size_t)bn * Kdim + t];
    __syncthreads();

    const float* xs = input_data + (size_t)bn * Sdim;
    if (t < Sdim) {
        float acc = s_wb[t];
        #pragma unroll
        for (int i = 0; i < Sdim; i++) acc += xs[i] * s_wW[i * Sdim + t];
        s_whs[t] = leaky(acc);
    }
    __syncthreads();

    if (t < Hdim) {
        float acc = 0.f;
        #pragma unroll
        for (int s = 0; s < Sdim; s++) acc += s_whs[s] * s_A1[s * Hdim + t];
        s_hx[t] = acc;
    }
    for (int e = t; e < Kdim * Sdim; e += 64) {
        const int k = e / Sdim, ss = e - k * Sdim;
        const float* xj = input_data + ((size_t)b * Ndim + s_idx[k]) * Sdim;
        float acc = s_wb[ss];
        #pragma unroll
        for (int i = 0; i < Sdim; i++) acc += xj[i] * s_wW[i * Sdim + ss];
        s_whj[k][ss] = leaky(acc);
    }
    __syncthreads();

    for (int e = t; e < Kdim * Hdim; e += 64) {
        const int k = e / Hdim, d = e - k * Hdim;
        float acc = s_hx[d] + s_b1[d];
        #pragma unroll
        for (int s = 0; s < Sdim; s++) acc += s_whj[k][s] * s_A1[(Sdim + s) * Hdim + d];
        s_hid[k][d] = leaky(acc);
    }
    __syncthreads();

    for (int e = t; e < Kdim * Cdim; e += 64) {
        const int k = e / Cdim, c = e - k * Cdim;
        float acc = s_b2f[c];
        #pragma unroll
        for (int d = 0; d < Hdim; d++) acc += s_hid[k][d] * s_A2f[d * Cdim + c];
        s_am[k][c] = leaky(acc);
    }
    __syncthreads();

    if (t < Kdim) {
        float m = -1e30f;
        #pragma unroll
        for (int c = 0; c < Cdim; c++) m = fmaxf(m, s_am[t][c]);
        float ex[Cdim]; float sum = 0.f;
        #pragma unroll
        for (int c = 0; c < Cdim; c++) { ex[c] = expf(s_am[t][c] - m); sum += ex[c]; }
        const float inv = 1.f / sum;
        #pragma unroll
        for (int c = 0; c < Cdim; c++) s_am[t][c] = ex[c] * inv;
        float nn = 0.f;
        #pragma unroll
        for (int s = 0; s < Sdim; s++) nn += s_whj[t][s] * s_whj[t][s];
        const float invn = 1.f / (sqrtf(nn) + 1e-8f);
        #pragma unroll
        for (int s = 0; s < Sdim; s++) s_wtn[t][s] = s_whj[t][s] * invn;
    }
    __syncthreads();

    float* op = out + (size_t)bn * (Cdim * Sdim);
    for (int e = t; e < Cdim * Sdim; e += 64) {
        const int c = e / Sdim, ss = e - c * Sdim;
        float acc = 0.f;
        #pragma unroll
        for (int k = 0; k < Kdim; k++) acc += s_am[k][c] * s_whj[k][ss];
        op[e] = acc;
    }

    float cl = 0.f, ds = 0.f;
    for (int e = t; e < Kdim * Kdim; e += 64) {
        const int k = e / Kdim, l = e - k * Kdim;
        float d = 0.f;
        #pragma unroll
        for (int s = 0; s < Sdim; s++) d += s_wtn[k][s] * s_wtn[l][s];
        ds += d;
        if (k != l) {
            float p = 0.f;
            #pragma unroll
            for (int c = 0; c < Cdim; c++) p += s_am[k][c] * s_am[l][c];
            p = fminf(fmaxf(p, 1e-4f), 1.f - 1e-4f);
            const float lp = logf(p);
            cl += (d >= 0.5f) ? -lp : lp;
        }
    }
    float whl = (t < Sdim) ? s_whs[t] : 0.f;
    #pragma unroll
    for (int off = 32; off > 0; off >>= 1) {
        cl  += __shfl_down(cl,  off);
        ds  += __shfl_down(ds,  off);
        whl += __shfl_down(whl, off);
    }
    if (t == 0) {
        atomicAdd(&out[OUT_SCALARS + 0], cl  * (1.f / (float)NB));
        atomicAdd(&out[OUT_SCALARS + 1], ds  * (1.f / ((float)NB * Kdim * Kdim)));
        atomicAdd(&out[OUT_SCALARS + 2], whl * (1.f / ((float)NB * Sdim)));
    }
}

extern "C" void kernel_launch(void* const* d_in, const int* in_sizes, int n_in,
                              void* d_out, int out_size, void* d_ws, size_t ws_size,
                              hipStream_t stream) {
    (void)in_sizes; (void)n_in; (void)out_size;
    // 0=fushed_features(unused), 1=input_data, 2=w_W, 3=w_b, 4=a1_W, 5=a1_b,
    // 6=a2_W, 7=a2_b, 8=adj_mx_topk_index
    const float* input_data = (const float*)d_in[1];
    const float* w_W  = (const float*)d_in[2];
    const float* w_b  = (const float*)d_in[3];
    const float* a1_W = (const float*)d_in[4];
    const float* a1_b = (const float*)d_in[5];
    const float* a2_W = (const float*)d_in[6];
    const float* a2_b = (const float*)d_in[7];
    const int*   topk = (const int*)d_in[8];
    float* out = (float*)d_out;
    float* ws  = (float*)d_ws;

    if (ws_size >= (size_t)WS_BASE_FLOATS * sizeof(float)) {
        hipLaunchKernelGGL(node_kernel, dim3(NODE_BLOCKS), dim3(256), 0, stream,
                           input_data, w_W, w_b, a1_W, a1_b, ws);
        hipLaunchKernelGGL(att_kernel, dim3((NB * Kdim + 255) / 256), dim3(256), 0, stream,
                           topk, a2_W, a2_b, ws);
        hipLaunchKernelGGL(bn_kernel, dim3(BN_BLOCKS), dim3(256), 0, stream,
                           topk, ws, out);
        hipLaunchKernelGGL(finalize, dim3(1), dim3(1024), 0, stream, ws, out);
    } else {
        hipLaunchKernelGGL(zero_scalars, dim3(1), dim3(64), 0, stream, out);
        hipLaunchKernelGGL(fused_kernel, dim3(NB), dim3(64), 0, stream,
                           input_data, w_W, w_b, a1_W, a1_b, a2_W, a2_b, topk, out);
    }
}

// Round 8
// 106.214 us; speedup vs baseline: 1.0432x; 1.0338x over previous
//
#include <hip/hip_runtime.h>
#include <math.h>

// Problem constants (from reference)
#define Bdim 32
#define Ndim 325
#define Kdim 20
#define Sdim 12      // S_IN == S_OUT == 12
#define Cdim 10
#define Hdim 48      // 4*S_OUT
#define NB   (Bdim*Ndim)                  // 10400 (b,n) pairs
#define OUT_SCALARS (NB*Cdim*Sdim)        // output_data floats, then 3 scalars
#define Tpairs (Kdim*(Kdim-1)/2)          // 190 upper-triangle pairs
#define BN_BLOCKS (NB/4)                  // 2600 blocks (4 bn each)
#define NODE_BLOCKS 260                   // 40 nodes per block
#define NPB 40

// Workspace layout (float offsets); all blocks 16B-aligned
#define O_WH  0                           // NB*12 node features wh
#define O_HX  (O_WH + NB*Sdim)            // NB*48: hx + a1_b (bias pre-folded)
#define O_HY  (O_HX + NB*Hdim)            // NB*48: hy
#define O_PCL (O_HY + NB*Hdim)            // BN_BLOCKS cluster-loss partials
#define O_PDS (O_PCL + BN_BLOCKS)         // BN_BLOCKS dist-sum partials
#define O_PWH (O_PDS + BN_BLOCKS)         // NODE_BLOCKS wh-sum partials
#define WS_BASE_FLOATS (O_PWH + NODE_BLOCKS)

__device__ __forceinline__ float leaky(float x) { return x >= 0.f ? x : 0.5f * x; }

// ---------------------------------------------------------------------------
// K1: grid-stride node kernel. 260 blocks x 256; 40 nodes per block.
// wh -> LDS + ws; hx(+b1), hy -> ws; per-BLOCK wh-sum partial.
// ---------------------------------------------------------------------------
__global__ __launch_bounds__(256)
void node_kernel(const float* __restrict__ x,
                 const float* __restrict__ wW, const float* __restrict__ wb,
                 const float* __restrict__ A1, const float* __restrict__ b1,
                 float* __restrict__ ws)
{
    __shared__ float s_wh[NPB][Sdim];
    __shared__ float s_r[4];
    const int tid = threadIdx.x;
    const int base = blockIdx.x * NPB;

    float v = 0.f;  // wh partial
    // wh: 40*12 = 480 elems
    #pragma unroll
    for (int rep = 0; rep < 2; rep++) {
        const int e = tid + rep * 256;
        if (e < NPB * Sdim) {
            const int n = e / Sdim, s = e - n * Sdim;
            const float* xr = x + (size_t)(base + n) * Sdim;
            float acc = wb[s];
            #pragma unroll
            for (int i = 0; i < Sdim; i++) acc += xr[i] * wW[i * Sdim + s];
            acc = leaky(acc);
            s_wh[n][s] = acc;
            ws[O_WH + (size_t)(base + n) * Sdim + s] = acc;
            v += acc;
        }
    }
    __syncthreads();

    // hx/hy: 40*96 = 3840 elems
    #pragma unroll
    for (int rep = 0; rep < 15; rep++) {
        const int e = tid + rep * 256;
        const int n = e / 96, r = e - n * 96;
        const int which = r / Hdim, d = r - which * Hdim;
        const float4 w0 = *(const float4*)&s_wh[n][0];
        const float4 w1 = *(const float4*)&s_wh[n][4];
        const float4 w2 = *(const float4*)&s_wh[n][8];
        const float* Ac = A1 + (which * Sdim) * Hdim + d;  // stride Hdim over s
        float acc = which ? 0.f : b1[d];                   // fold a1_b into hx
        acc += w0.x*Ac[0*Hdim] + w0.y*Ac[1*Hdim] + w0.z*Ac[2*Hdim] + w0.w*Ac[3*Hdim]
             + w1.x*Ac[4*Hdim] + w1.y*Ac[5*Hdim] + w1.z*Ac[6*Hdim] + w1.w*Ac[7*Hdim]
             + w2.x*Ac[8*Hdim] + w2.y*Ac[9*Hdim] + w2.z*Ac[10*Hdim] + w2.w*Ac[11*Hdim];
        ws[(which ? O_HY : O_HX) + (size_t)(base + n) * Hdim + d] = acc;
    }

    // block-reduce wh partial
    #pragma unroll
    for (int off = 32; off > 0; off >>= 1) v += __shfl_down(v, off);
    if ((tid & 63) == 0) s_r[tid >> 6] = v;
    __syncthreads();
    if (tid == 0) ws[O_PWH + blockIdx.x] = s_r[0] + s_r[1] + s_r[2] + s_r[3];
}

// ---------------------------------------------------------------------------
// K2 (merged att+bn): 4 bn per 256-thread block.
// Lanes 0..79:  one edge each — logits from global hx/hy with wave-uniform
//               A2 indexing (s_load, zero LDS), in-register softmax -> s_am.
// Lanes 80..255: gather the 240 whj float4s (topk read direct from L2).
// One __syncthreads, then wave-synchronous per-slot tail (invn || einsum),
// 190-pair symmetric loss, block partials to ws. No fences/global atomics.
// ---------------------------------------------------------------------------
__global__ __launch_bounds__(256)
void mega_kernel(const int* __restrict__ topk,
                 const float* __restrict__ A2, const float* __restrict__ b2,
                 float* __restrict__ ws, float* __restrict__ out)
{
    __shared__ float s_whj [4][Kdim][12];   // 48B rows, float4-aligned
    __shared__ float s_am  [4][Kdim][12];   // probs, c padded with zeros
    __shared__ float s_invn[4][Kdim];
    __shared__ float s_red[2][4];

    const int tid = threadIdx.x;
    const int slot = tid >> 6, t = tid & 63;

    if (tid < 80) {
        // ---- edge lane: attention logits + softmax for edge e = tid ----
        const int gid = blockIdx.x * 80 + tid;
        const int bn_e = gid / Kdim;             // = blockIdx.x*4 + tid/20
        const int b_e  = bn_e / Ndim;
        const int j    = topk[gid];
        const int ek   = tid / 20, kk = tid - ek * 20;  // (slot, k) of this edge

        const float4* hx4 = (const float4*)(ws + O_HX + (size_t)bn_e * Hdim);
        const float4* hy4 = (const float4*)(ws + O_HY + ((size_t)b_e * Ndim + j) * Hdim);

        float acc[Cdim];
        #pragma unroll
        for (int c = 0; c < Cdim; c++) acc[c] = b2[c];
        #pragma unroll
        for (int q = 0; q < 12; q++) {
            const float4 xv = hx4[q], yv = hy4[q];
            const float hh[4] = { leaky(xv.x + yv.x), leaky(xv.y + yv.y),
                                  leaky(xv.z + yv.z), leaky(xv.w + yv.w) };
            #pragma unroll
            for (int i = 0; i < 4; i++) {
                #pragma unroll
                for (int c = 0; c < Cdim; c++)
                    acc[c] += hh[i] * A2[(q * 4 + i) * Cdim + c];
            }
        }
        float m = -1e30f;
        #pragma unroll
        for (int c = 0; c < Cdim; c++) { acc[c] = leaky(acc[c]); m = fmaxf(m, acc[c]); }
        float sum = 0.f;
        #pragma unroll
        for (int c = 0; c < Cdim; c++) { acc[c] = __expf(acc[c] - m); sum += acc[c]; }
        const float inv = 1.f / sum;
        *(float4*)&s_am[ek][kk][0] = make_float4(acc[0]*inv, acc[1]*inv, acc[2]*inv, acc[3]*inv);
        *(float4*)&s_am[ek][kk][4] = make_float4(acc[4]*inv, acc[5]*inv, acc[6]*inv, acc[7]*inv);
        *(float4*)&s_am[ek][kk][8] = make_float4(acc[8]*inv, acc[9]*inv, 0.f, 0.f);
    } else {
        // ---- gather lanes: 240 float4s of whj across lanes 80..255 ----
        for (int i = tid - 80; i < 240; i += 176) {
            const int kf = i / 3, q = i - kf * 3;          // kf in [0,80)
            const int sl = kf / 20, k = kf - sl * 20;
            const int gidx = blockIdx.x * 80 + kf;
            const int bn_i = gidx / Kdim;
            const int b_i  = bn_i / Ndim;
            const int j    = topk[gidx];
            const float4 v = *(const float4*)(ws + O_WH + ((size_t)b_i * Ndim + j) * Sdim + q * 4);
            *(float4*)&s_whj[sl][k][q * 4] = v;
        }
    }
    __syncthreads();                         // the ONLY mid-kernel block barrier

    const int bn = blockIdx.x * 4 + slot;
    float cl = 0.f, ds = 0.f;

    if (t < Kdim) {
        // per-k norm factor + diagonal dist contribution
        const float4 w0 = *(const float4*)&s_whj[slot][t][0];
        const float4 w1 = *(const float4*)&s_whj[slot][t][4];
        const float4 w2 = *(const float4*)&s_whj[slot][t][8];
        const float nn = w0.x*w0.x + w0.y*w0.y + w0.z*w0.z + w0.w*w0.w
                       + w1.x*w1.x + w1.y*w1.y + w1.z*w1.z + w1.w*w1.w
                       + w2.x*w2.x + w2.y*w2.y + w2.z*w2.z + w2.w*w2.w;
        const float invn = 1.f / (sqrtf(nn) + 1e-8f);
        s_invn[slot][t] = invn;
        ds += nn * invn * invn;               // dist_mat diagonal term
    } else if (t < Kdim + 30) {
        // output einsum: lane = (c, s-quad), float4 stores
        const int e = t - Kdim, c = e / 3, sq = e - c * 3;
        float4 o = make_float4(0.f, 0.f, 0.f, 0.f);
        #pragma unroll
        for (int k = 0; k < Kdim; k++) {
            const float a = s_am[slot][k][c];
            const float4 w = *(const float4*)&s_whj[slot][k][sq * 4];
            o.x += a * w.x; o.y += a * w.y; o.z += a * w.z; o.w += a * w.w;
        }
        *(float4*)(out + (size_t)bn * (Cdim * Sdim) + c * Sdim + sq * 4) = o;
    }
    __builtin_amdgcn_wave_barrier();         // invn -> loss is intra-wave

    // loss: 190 upper-triangle pairs, doubled (dist/prob are symmetric)
    #pragma unroll
    for (int it = 0; it < 3; it++) {
        const int e = t + it * 64;
        if (e < Tpairs) {
            const int r = Tpairs - 1 - e;
            const int m = (int)((sqrtf((float)(8 * r + 1)) - 1.f) * 0.5f + 1e-4f);
            const int k = Kdim - 2 - m;
            const int l = Kdim - 1 - (r - (m * (m + 1)) / 2);

            const float4 a0 = *(const float4*)&s_whj[slot][k][0];
            const float4 a1 = *(const float4*)&s_whj[slot][k][4];
            const float4 a2 = *(const float4*)&s_whj[slot][k][8];
            const float4 c0 = *(const float4*)&s_whj[slot][l][0];
            const float4 c1 = *(const float4*)&s_whj[slot][l][4];
            const float4 c2 = *(const float4*)&s_whj[slot][l][8];
            const float draw = a0.x*c0.x + a0.y*c0.y + a0.z*c0.z + a0.w*c0.w
                             + a1.x*c1.x + a1.y*c1.y + a1.z*c1.z + a1.w*c1.w
                             + a2.x*c2.x + a2.y*c2.y + a2.z*c2.z + a2.w*c2.w;
            const float d = draw * s_invn[slot][k] * s_invn[slot][l];

            const float4 p0 = *(const float4*)&s_am[slot][k][0];
            const float4 p1 = *(const float4*)&s_am[slot][k][4];
            const float4 p2 = *(const float4*)&s_am[slot][k][8];
            const float4 q0 = *(const float4*)&s_am[slot][l][0];
            const float4 q1 = *(const float4*)&s_am[slot][l][4];
            const float4 q2 = *(const float4*)&s_am[slot][l][8];
            float p = p0.x*q0.x + p0.y*q0.y + p0.z*q0.z + p0.w*q0.w
                    + p1.x*q1.x + p1.y*q1.y + p1.z*q1.z + p1.w*q1.w
                    + p2.x*q2.x + p2.y*q2.y + p2.z*q2.z + p2.w*q2.w;

            p = fminf(fmaxf(p, 1e-4f), 1.f - 1e-4f);
            const float lp = __logf(p);
            ds += 2.f * d;
            cl += 2.f * ((d >= 0.5f) ? -lp : lp);
        }
    }

    // wave reduce, then cross-slot reduce -> one block partial (plain stores)
    #pragma unroll
    for (int off = 32; off > 0; off >>= 1) {
        cl += __shfl_down(cl, off);
        ds += __shfl_down(ds, off);
    }
    if (t == 0) { s_red[0][slot] = cl; s_red[1][slot] = ds; }
    __syncthreads();
    if (tid == 0) {
        ws[O_PCL + blockIdx.x] = s_red[0][0] + s_red[0][1] + s_red[0][2] + s_red[0][3];
        ws[O_PDS + blockIdx.x] = s_red[1][0] + s_red[1][1] + s_red[1][2] + s_red[1][3];
    }
}

// ---------------------------------------------------------------------------
// K3: reduce partials -> 3 output scalars (tiny)
// ---------------------------------------------------------------------------
__global__ __launch_bounds__(1024)
void finalize(const float* __restrict__ ws, float* __restrict__ out)
{
    const int t = threadIdx.x;
    float cl = 0.f, ds = 0.f, wm = 0.f;
    for (int i = t; i < BN_BLOCKS; i += 1024) {
        cl += ws[O_PCL + i]; ds += ws[O_PDS + i];
    }
    if (t < NODE_BLOCKS) wm = ws[O_PWH + t];
    #pragma unroll
    for (int off = 32; off > 0; off >>= 1) {
        cl += __shfl_down(cl, off);
        ds += __shfl_down(ds, off);
        wm += __shfl_down(wm, off);
    }
    __shared__ float r[3][16];
    const int w = t >> 6, lane = t & 63;
    if (lane == 0) { r[0][w] = cl; r[1][w] = ds; r[2][w] = wm; }
    __syncthreads();
    if (t == 0) {
        float c = 0.f, d = 0.f, m = 0.f;
        #pragma unroll
        for (int i = 0; i < 16; i++) { c += r[0][i]; d += r[1][i]; m += r[2][i]; }
        out[OUT_SCALARS + 0] = c * (1.f / (float)NB);
        out[OUT_SCALARS + 1] = d * (1.f / ((float)NB * Kdim * Kdim));
        out[OUT_SCALARS + 2] = m * (1.f / ((float)NB * Sdim));
    }
}

// ---------------------------------------------------------------------------
// Fallback: round-1 monolithic kernel (used only if ws is too small)
// ---------------------------------------------------------------------------
__global__ void zero_scalars(float* out) {
    const int t = threadIdx.x;
    if (t < 3) out[OUT_SCALARS + t] = 0.f;
}

__global__ __launch_bounds__(64)
void fused_kernel(const float* __restrict__ input_data,
                  const float* __restrict__ w_W,  const float* __restrict__ w_b,
                  const float* __restrict__ a1_W, const float* __restrict__ a1_b,
                  const float* __restrict__ a2_W, const float* __restrict__ a2_b,
                  const int*   __restrict__ topk,
                  float* __restrict__ out)
{
    __shared__ float s_wW[Sdim * Sdim];
    __shared__ float s_wb[Sdim];
    __shared__ float s_A1[2 * Sdim * Hdim];
    __shared__ float s_b1[Hdim];
    __shared__ float s_A2f[Hdim * Cdim];
    __shared__ float s_b2f[Cdim];
    __shared__ float s_whs[Sdim];
    __shared__ float s_hx[Hdim];
    __shared__ float s_whj[Kdim][Sdim + 1];
    __shared__ float s_hid[Kdim][Hdim + 1];
    __shared__ float s_am [Kdim][Cdim + 1];
    __shared__ float s_wtn[Kdim][Sdim + 1];
    __shared__ int   s_idx[Kdim];

    const int t = threadIdx.x, bn = blockIdx.x, b = bn / Ndim;

    for (int i = t; i < Sdim * Sdim; i += 64)      s_wW[i] = w_W[i];
    if (t < Sdim)                                  s_wb[t] = w_b[t];
    for (int i = t; i < 2 * Sdim * Hdim; i += 64)  s_A1[i] = a1_W[i];
    if (t < Hdim)                                  s_b1[t] = a1_b[t];
    for (int i = t; i < Hdim * Cdim; i += 64)      s_A2f[i] = a2_W[i];
    if (t < Cdim)                                  s_b2f[t] = a2_b[t];
    if (t < Kdim)                                  s_idx[t] = topk[(size_t)bn * Kdim + t];
    __syncthreads();

    const float* xs = input_data + (size_t)bn * Sdim;
    if (t < Sdim) {
        float acc = s_wb[t];
        #pragma unroll
        for (int i = 0; i < Sdim; i++) acc += xs[i] * s_wW[i * Sdim + t];
        s_whs[t] = leaky(acc);
    }
    __syncthreads();

    if (t < Hdim) {
        float acc = 0.f;
        #pragma unroll
        for (int s = 0; s < Sdim; s++) acc += s_whs[s] * s_A1[s * Hdim + t];
        s_hx[t] = acc;
    }
    for (int e = t; e < Kdim * Sdim; e += 64) {
        const int k = e / Sdim, ss = e - k * Sdim;
        const float* xj = input_data + ((size_t)b * Ndim + s_idx[k]) * Sdim;
        float acc = s_wb[ss];
        #pragma unroll
        for (int i = 0; i < Sdim; i++) acc += xj[i] * s_wW[i * Sdim + ss];
        s_whj[k][ss] = leaky(acc);
    }
    __syncthreads();

    for (int e = t; e < Kdim * Hdim; e += 64) {
        const int k = e / Hdim, d = e - k * Hdim;
        float acc = s_hx[d] + s_b1[d];
        #pragma unroll
        for (int s = 0; s < Sdim; s++) acc += s_whj[k][s] * s_A1[(Sdim + s) * Hdim + d];
        s_hid[k][d] = leaky(acc);
    }
    __syncthreads();

    for (int e = t; e < Kdim * Cdim; e += 64) {
        const int k = e / Cdim, c = e - k * Cdim;
        float acc = s_b2f[c];
        #pragma unroll
        for (int d = 0; d < Hdim; d++) acc += s_hid[k][d] * s_A2f[d * Cdim + c];
        s_am[k][c] = leaky(acc);
    }
    __syncthreads();

    if (t < Kdim) {
        float m = -1e30f;
        #pragma unroll
        for (int c = 0; c < Cdim; c++) m = fmaxf(m, s_am[t][c]);
        float ex[Cdim]; float sum = 0.f;
        #pragma unroll
        for (int c = 0; c < Cdim; c++) { ex[c] = expf(s_am[t][c] - m); sum += ex[c]; }
        const float inv = 1.f / sum;
        #pragma unroll
        for (int c = 0; c < Cdim; c++) s_am[t][c] = ex[c] * inv;
        float nn = 0.f;
        #pragma unroll
        for (int s = 0; s < Sdim; s++) nn += s_whj[t][s] * s_whj[t][s];
        const float invn = 1.f / (sqrtf(nn) + 1e-8f);
        #pragma unroll
        for (int s = 0; s < Sdim; s++) s_wtn[t][s] = s_whj[t][s] * invn;
    }
    __syncthreads();

    float* op = out + (size_t)bn * (Cdim * Sdim);
    for (int e = t; e < Cdim * Sdim; e += 64) {
        const int c = e / Sdim, ss = e - c * Sdim;
        float acc = 0.f;
        #pragma unroll
        for (int k = 0; k < Kdim; k++) acc += s_am[k][c] * s_whj[k][ss];
        op[e] = acc;
    }

    float cl = 0.f, ds = 0.f;
    for (int e = t; e < Kdim * Kdim; e += 64) {
        const int k = e / Kdim, l = e - k * Kdim;
        float d = 0.f;
        #pragma unroll
        for (int s = 0; s < Sdim; s++) d += s_wtn[k][s] * s_wtn[l][s];
        ds += d;
        if (k != l) {
            float p = 0.f;
            #pragma unroll
            for (int c = 0; c < Cdim; c++) p += s_am[k][c] * s_am[l][c];
            p = fminf(fmaxf(p, 1e-4f), 1.f - 1e-4f);
            const float lp = logf(p);
            cl += (d >= 0.5f) ? -lp : lp;
        }
    }
    float whl = (t < Sdim) ? s_whs[t] : 0.f;
    #pragma unroll
    for (int off = 32; off > 0; off >>= 1) {
        cl  += __shfl_down(cl,  off);
        ds  += __shfl_down(ds,  off);
        whl += __shfl_down(whl, off);
    }
    if (t == 0) {
        atomicAdd(&out[OUT_SCALARS + 0], cl  * (1.f / (float)NB));
        atomicAdd(&out[OUT_SCALARS + 1], ds  * (1.f / ((float)NB * Kdim * Kdim)));
        atomicAdd(&out[OUT_SCALARS + 2], whl * (1.f / ((float)NB * Sdim)));
    }
}

extern "C" void kernel_launch(void* const* d_in, const int* in_sizes, int n_in,
                              void* d_out, int out_size, void* d_ws, size_t ws_size,
                              hipStream_t stream) {
    (void)in_sizes; (void)n_in; (void)out_size;
    // 0=fushed_features(unused), 1=input_data, 2=w_W, 3=w_b, 4=a1_W, 5=a1_b,
    // 6=a2_W, 7=a2_b, 8=adj_mx_topk_index
    const float* input_data = (const float*)d_in[1];
    const float* w_W  = (const float*)d_in[2];
    const float* w_b  = (const float*)d_in[3];
    const float* a1_W = (const float*)d_in[4];
    const float* a1_b = (const float*)d_in[5];
    const float* a2_W = (const float*)d_in[6];
    const float* a2_b = (const float*)d_in[7];
    const int*   topk = (const int*)d_in[8];
    float* out = (float*)d_out;
    float* ws  = (float*)d_ws;

    if (ws_size >= (size_t)WS_BASE_FLOATS * sizeof(float)) {
        hipLaunchKernelGGL(node_kernel, dim3(NODE_BLOCKS), dim3(256), 0, stream,
                           input_data, w_W, w_b, a1_W, a1_b, ws);
        hipLaunchKernelGGL(mega_kernel, dim3(BN_BLOCKS), dim3(256), 0, stream,
                           topk, a2_W, a2_b, ws, out);
        hipLaunchKernelGGL(finalize, dim3(1), dim3(1024), 0, stream, ws, out);
    } else {
        hipLaunchKernelGGL(zero_scalars, dim3(1), dim3(64), 0, stream, out);
        hipLaunchKernelGGL(fused_kernel, dim3(NB), dim3(64), 0, stream,
                           input_data, w_W, w_b, a1_W, a1_b, a2_W, a2_b, topk, out);
    }
}

// Round 9
// 103.938 us; speedup vs baseline: 1.0661x; 1.0219x over previous
//
#include <hip/hip_runtime.h>
#include <math.h>

// Problem constants (from reference)
#define Bdim 32
#define Ndim 325
#define Kdim 20
#define Sdim 12      // S_IN == S_OUT == 12
#define Cdim 10
#define Hdim 48      // 4*S_OUT
#define NB   (Bdim*Ndim)                  // 10400 (b,n) pairs
#define OUT_SCALARS (NB*Cdim*Sdim)        // output_data floats, then 3 scalars
#define Tpairs (Kdim*(Kdim-1)/2)          // 190 upper-triangle pairs
#define BN_BLOCKS (NB/4)                  // 2600 blocks (4 bn each)
#define NODE_BLOCKS 260                   // 40 nodes per block
#define NPB 40

// Workspace layout (float offsets); all blocks 16B-aligned
#define O_WH  0                           // NB*12 node features wh
#define O_HX  (O_WH + NB*Sdim)            // NB*48: hx + a1_b (bias pre-folded)
#define O_HY  (O_HX + NB*Hdim)            // NB*48: hy
#define O_PCL (O_HY + NB*Hdim)            // BN_BLOCKS cluster-loss partials
#define O_PDS (O_PCL + BN_BLOCKS)         // BN_BLOCKS dist-sum partials
#define O_PWH (O_PDS + BN_BLOCKS)         // NODE_BLOCKS wh-sum partials
#define WS_BASE_FLOATS (O_PWH + NODE_BLOCKS)

__device__ __forceinline__ float leaky(float x) { return x >= 0.f ? x : 0.5f * x; }

// ---------------------------------------------------------------------------
// K1: grid-stride node kernel. 260 blocks x 256; 40 nodes per block.
// wh -> LDS + ws; hx(+b1), hy -> ws; per-BLOCK wh-sum partial.
// ---------------------------------------------------------------------------
__global__ __launch_bounds__(256)
void node_kernel(const float* __restrict__ x,
                 const float* __restrict__ wW, const float* __restrict__ wb,
                 const float* __restrict__ A1, const float* __restrict__ b1,
                 float* __restrict__ ws)
{
    __shared__ float s_wh[NPB][Sdim];
    __shared__ float s_r[4];
    const int tid = threadIdx.x;
    const int base = blockIdx.x * NPB;

    float v = 0.f;  // wh partial
    // wh: 40*12 = 480 elems
    #pragma unroll
    for (int rep = 0; rep < 2; rep++) {
        const int e = tid + rep * 256;
        if (e < NPB * Sdim) {
            const int n = e / Sdim, s = e - n * Sdim;
            const float* xr = x + (size_t)(base + n) * Sdim;
            float acc = wb[s];
            #pragma unroll
            for (int i = 0; i < Sdim; i++) acc += xr[i] * wW[i * Sdim + s];
            acc = leaky(acc);
            s_wh[n][s] = acc;
            ws[O_WH + (size_t)(base + n) * Sdim + s] = acc;
            v += acc;
        }
    }
    __syncthreads();

    // hx/hy: 40*96 = 3840 elems
    #pragma unroll
    for (int rep = 0; rep < 15; rep++) {
        const int e = tid + rep * 256;
        const int n = e / 96, r = e - n * 96;
        const int which = r / Hdim, d = r - which * Hdim;
        const float4 w0 = *(const float4*)&s_wh[n][0];
        const float4 w1 = *(const float4*)&s_wh[n][4];
        const float4 w2 = *(const float4*)&s_wh[n][8];
        const float* Ac = A1 + (which * Sdim) * Hdim + d;  // stride Hdim over s
        float acc = which ? 0.f : b1[d];                   // fold a1_b into hx
        acc += w0.x*Ac[0*Hdim] + w0.y*Ac[1*Hdim] + w0.z*Ac[2*Hdim] + w0.w*Ac[3*Hdim]
             + w1.x*Ac[4*Hdim] + w1.y*Ac[5*Hdim] + w1.z*Ac[6*Hdim] + w1.w*Ac[7*Hdim]
             + w2.x*Ac[8*Hdim] + w2.y*Ac[9*Hdim] + w2.z*Ac[10*Hdim] + w2.w*Ac[11*Hdim];
        ws[(which ? O_HY : O_HX) + (size_t)(base + n) * Hdim + d] = acc;
    }

    // block-reduce wh partial
    #pragma unroll
    for (int off = 32; off > 0; off >>= 1) v += __shfl_down(v, off);
    if ((tid & 63) == 0) s_r[tid >> 6] = v;
    __syncthreads();
    if (tid == 0) ws[O_PWH + blockIdx.x] = s_r[0] + s_r[1] + s_r[2] + s_r[3];
}

// ---------------------------------------------------------------------------
// K2 (merged att+bn): 4 bn per 256-thread block.
// Phase 0: stage A2 (480 floats, contiguous) into LDS; one barrier.
// Phase 1: lanes 0..159 = 2 lanes per edge (80 edges): each half computes
//          24 d's of the logit dot from LDS A2 (<=2 distinct LDS addrs per
//          wave instr -> broadcast, free), shfl_xor combine, softmax on even
//          lane -> s_am. Lanes 160..255 gather the 240 whj float4s.
// Phase 2 (after 2nd barrier): wave-synchronous tail (invn || einsum),
//          190-pair symmetric loss, block partials. No fences/global atomics.
// ---------------------------------------------------------------------------
__global__ __launch_bounds__(256)
void mega_kernel(const int* __restrict__ topk,
                 const float* __restrict__ A2, const float* __restrict__ b2,
                 float* __restrict__ ws, float* __restrict__ out)
{
    __shared__ float s_A2  [Hdim * Cdim];   // 480 floats, contiguous d*10+c
    __shared__ float s_whj [4][Kdim][12];   // 48B rows, float4-aligned
    __shared__ float s_am  [4][Kdim][12];   // probs, c padded with zeros
    __shared__ float s_invn[4][Kdim];
    __shared__ float s_red[2][4];

    const int tid = threadIdx.x;
    const int slot = tid >> 6, t = tid & 63;

    // ---- phase 0: stage A2 (120 float4) ----
    if (tid < 120) *(float4*)&s_A2[tid * 4] = *(const float4*)&A2[tid * 4];
    __syncthreads();

    if (tid < 160) {
        // ---- edge pair lanes: e = tid>>1, half = tid&1, 24 d's each ----
        const int e = tid >> 1, half = tid & 1;
        const int gid = blockIdx.x * 80 + e;
        const int bn_e = gid / Kdim;
        const int b_e  = bn_e / Ndim;
        const int j    = topk[gid];
        const int ek   = e / 20, kk = e - ek * 20;   // (slot, k) of this edge

        const float4* hx4 = (const float4*)(ws + O_HX + (size_t)bn_e * Hdim) + half * 6;
        const float4* hy4 = (const float4*)(ws + O_HY + ((size_t)b_e * Ndim + j) * Hdim) + half * 6;

        float acc[Cdim];
        #pragma unroll
        for (int c = 0; c < Cdim; c++) acc[c] = 0.f;
        #pragma unroll
        for (int q = 0; q < 6; q++) {
            const float4 xv = hx4[q], yv = hy4[q];
            const float hh[4] = { leaky(xv.x + yv.x), leaky(xv.y + yv.y),
                                  leaky(xv.z + yv.z), leaky(xv.w + yv.w) };
            #pragma unroll
            for (int i = 0; i < 4; i++) {
                const int d = half * 24 + q * 4 + i;
                #pragma unroll
                for (int c = 0; c < Cdim; c++)
                    acc[c] += hh[i] * s_A2[d * Cdim + c];
            }
        }
        float full[Cdim];
        #pragma unroll
        for (int c = 0; c < Cdim; c++) full[c] = acc[c] + __shfl_xor(acc[c], 1);
        if (half == 0) {
            float m = -1e30f;
            #pragma unroll
            for (int c = 0; c < Cdim; c++) { full[c] = leaky(full[c] + b2[c]); m = fmaxf(m, full[c]); }
            float sum = 0.f;
            #pragma unroll
            for (int c = 0; c < Cdim; c++) { full[c] = __expf(full[c] - m); sum += full[c]; }
            const float inv = 1.f / sum;
            *(float4*)&s_am[ek][kk][0] = make_float4(full[0]*inv, full[1]*inv, full[2]*inv, full[3]*inv);
            *(float4*)&s_am[ek][kk][4] = make_float4(full[4]*inv, full[5]*inv, full[6]*inv, full[7]*inv);
            *(float4*)&s_am[ek][kk][8] = make_float4(full[8]*inv, full[9]*inv, 0.f, 0.f);
        }
    } else {
        // ---- gather lanes (96): 240 float4s of whj ----
        for (int i = tid - 160; i < 240; i += 96) {
            const int kf = i / 3, q = i - kf * 3;          // kf in [0,80)
            const int sl = kf / 20, k = kf - sl * 20;
            const int gidx = blockIdx.x * 80 + kf;
            const int bn_i = gidx / Kdim;
            const int b_i  = bn_i / Ndim;
            const int j    = topk[gidx];
            const float4 v = *(const float4*)(ws + O_WH + ((size_t)b_i * Ndim + j) * Sdim + q * 4);
            *(float4*)&s_whj[sl][k][q * 4] = v;
        }
    }
    __syncthreads();

    const int bn = blockIdx.x * 4 + slot;
    float cl = 0.f, ds = 0.f;

    if (t < Kdim) {
        // per-k norm factor + diagonal dist contribution
        const float4 w0 = *(const float4*)&s_whj[slot][t][0];
        const float4 w1 = *(const float4*)&s_whj[slot][t][4];
        const float4 w2 = *(const float4*)&s_whj[slot][t][8];
        const float nn = w0.x*w0.x + w0.y*w0.y + w0.z*w0.z + w0.w*w0.w
                       + w1.x*w1.x + w1.y*w1.y + w1.z*w1.z + w1.w*w1.w
                       + w2.x*w2.x + w2.y*w2.y + w2.z*w2.z + w2.w*w2.w;
        const float invn = 1.f / (sqrtf(nn) + 1e-8f);
        s_invn[slot][t] = invn;
        ds += nn * invn * invn;               // dist_mat diagonal term
    } else if (t < Kdim + 30) {
        // output einsum: lane = (c, s-quad), float4 stores
        const int e = t - Kdim, c = e / 3, sq = e - c * 3;
        float4 o = make_float4(0.f, 0.f, 0.f, 0.f);
        #pragma unroll
        for (int k = 0; k < Kdim; k++) {
            const float a = s_am[slot][k][c];
            const float4 w = *(const float4*)&s_whj[slot][k][sq * 4];
            o.x += a * w.x; o.y += a * w.y; o.z += a * w.z; o.w += a * w.w;
        }
        *(float4*)(out + (size_t)bn * (Cdim * Sdim) + c * Sdim + sq * 4) = o;
    }
    __builtin_amdgcn_wave_barrier();         // invn -> loss is intra-wave

    // loss: 190 upper-triangle pairs, doubled (dist/prob are symmetric)
    #pragma unroll
    for (int it = 0; it < 3; it++) {
        const int e = t + it * 64;
        if (e < Tpairs) {
            const int r = Tpairs - 1 - e;
            const int m = (int)((sqrtf((float)(8 * r + 1)) - 1.f) * 0.5f + 1e-4f);
            const int k = Kdim - 2 - m;
            const int l = Kdim - 1 - (r - (m * (m + 1)) / 2);

            const float4 a0 = *(const float4*)&s_whj[slot][k][0];
            const float4 a1 = *(const float4*)&s_whj[slot][k][4];
            const float4 a2 = *(const float4*)&s_whj[slot][k][8];
            const float4 c0 = *(const float4*)&s_whj[slot][l][0];
            const float4 c1 = *(const float4*)&s_whj[slot][l][4];
            const float4 c2 = *(const float4*)&s_whj[slot][l][8];
            const float draw = a0.x*c0.x + a0.y*c0.y + a0.z*c0.z + a0.w*c0.w
                             + a1.x*c1.x + a1.y*c1.y + a1.z*c1.z + a1.w*c1.w
                             + a2.x*c2.x + a2.y*c2.y + a2.z*c2.z + a2.w*c2.w;
            const float d = draw * s_invn[slot][k] * s_invn[slot][l];

            const float4 p0 = *(const float4*)&s_am[slot][k][0];
            const float4 p1 = *(const float4*)&s_am[slot][k][4];
            const float4 p2 = *(const float4*)&s_am[slot][k][8];
            const float4 q0 = *(const float4*)&s_am[slot][l][0];
            const float4 q1 = *(const float4*)&s_am[slot][l][4];
            const float4 q2 = *(const float4*)&s_am[slot][l][8];
            float p = p0.x*q0.x + p0.y*q0.y + p0.z*q0.z + p0.w*q0.w
                    + p1.x*q1.x + p1.y*q1.y + p1.z*q1.z + p1.w*q1.w
                    + p2.x*q2.x + p2.y*q2.y + p2.z*q2.z + p2.w*q2.w;

            p = fminf(fmaxf(p, 1e-4f), 1.f - 1e-4f);
            const float lp = __logf(p);
            ds += 2.f * d;
            cl += 2.f * ((d >= 0.5f) ? -lp : lp);
        }
    }

    // wave reduce, then cross-slot reduce -> one block partial (plain stores)
    #pragma unroll
    for (int off = 32; off > 0; off >>= 1) {
        cl += __shfl_down(cl, off);
        ds += __shfl_down(ds, off);
    }
    if (t == 0) { s_red[0][slot] = cl; s_red[1][slot] = ds; }
    __syncthreads();
    if (tid == 0) {
        ws[O_PCL + blockIdx.x] = s_red[0][0] + s_red[0][1] + s_red[0][2] + s_red[0][3];
        ws[O_PDS + blockIdx.x] = s_red[1][0] + s_red[1][1] + s_red[1][2] + s_red[1][3];
    }
}

// ---------------------------------------------------------------------------
// K3: reduce partials -> 3 output scalars (tiny)
// ---------------------------------------------------------------------------
__global__ __launch_bounds__(1024)
void finalize(const float* __restrict__ ws, float* __restrict__ out)
{
    const int t = threadIdx.x;
    float cl = 0.f, ds = 0.f, wm = 0.f;
    for (int i = t; i < BN_BLOCKS; i += 1024) {
        cl += ws[O_PCL + i]; ds += ws[O_PDS + i];
    }
    if (t < NODE_BLOCKS) wm = ws[O_PWH + t];
    #pragma unroll
    for (int off = 32; off > 0; off >>= 1) {
        cl += __shfl_down(cl, off);
        ds += __shfl_down(ds, off);
        wm += __shfl_down(wm, off);
    }
    __shared__ float r[3][16];
    const int w = t >> 6, lane = t & 63;
    if (lane == 0) { r[0][w] = cl; r[1][w] = ds; r[2][w] = wm; }
    __syncthreads();
    if (t == 0) {
        float c = 0.f, d = 0.f, m = 0.f;
        #pragma unroll
        for (int i = 0; i < 16; i++) { c += r[0][i]; d += r[1][i]; m += r[2][i]; }
        out[OUT_SCALARS + 0] = c * (1.f / (float)NB);
        out[OUT_SCALARS + 1] = d * (1.f / ((float)NB * Kdim * Kdim));
        out[OUT_SCALARS + 2] = m * (1.f / ((float)NB * Sdim));
    }
}

// ---------------------------------------------------------------------------
// Fallback: round-1 monolithic kernel (used only if ws is too small)
// ---------------------------------------------------------------------------
__global__ void zero_scalars(float* out) {
    const int t = threadIdx.x;
    if (t < 3) out[OUT_SCALARS + t] = 0.f;
}

__global__ __launch_bounds__(64)
void fused_kernel(const float* __restrict__ input_data,
                  const float* __restrict__ w_W,  const float* __restrict__ w_b,
                  const float* __restrict__ a1_W, const float* __restrict__ a1_b,
                  const float* __restrict__ a2_W, const float* __restrict__ a2_b,
                  const int*   __restrict__ topk,
                  float* __restrict__ out)
{
    __shared__ float s_wW[Sdim * Sdim];
    __shared__ float s_wb[Sdim];
    __shared__ float s_A1[2 * Sdim * Hdim];
    __shared__ float s_b1[Hdim];
    __shared__ float s_A2f[Hdim * Cdim];
    __shared__ float s_b2f[Cdim];
    __shared__ float s_whs[Sdim];
    __shared__ float s_hx[Hdim];
    __shared__ float s_whj[Kdim][Sdim + 1];
    __shared__ float s_hid[Kdim][Hdim + 1];
    __shared__ float s_am [Kdim][Cdim + 1];
    __shared__ float s_wtn[Kdim][Sdim + 1];
    __shared__ int   s_idx[Kdim];

    const int t = threadIdx.x, bn = blockIdx.x, b = bn / Ndim;

    for (int i = t; i < Sdim * Sdim; i += 64)      s_wW[i] = w_W[i];
    if (t < Sdim)                                  s_wb[t] = w_b[t];
    for (int i = t; i < 2 * Sdim * Hdim; i += 64)  s_A1[i] = a1_W[i];
    if (t < Hdim)                                  s_b1[t] = a1_b[t];
    for (int i = t; i < Hdim * Cdim; i += 64)      s_A2f[i] = a2_W[i];
    if (t < Cdim)                                  s_b2f[t] = a2_b[t];
    if (t < Kdim)                                  s_idx[t] = topk[(size_t)bn * Kdim + t];
    __syncthreads();

    const float* xs = input_data + (size_t)bn * Sdim;
    if (t < Sdim) {
        float acc = s_wb[t];
        #pragma unroll
        for (int i = 0; i < Sdim; i++) acc += xs[i] * s_wW[i * Sdim + t];
        s_whs[t] = leaky(acc);
    }
    __syncthreads();

    if (t < Hdim) {
        float acc = 0.f;
        #pragma unroll
        for (int s = 0; s < Sdim; s++) acc += s_whs[s] * s_A1[s * Hdim + t];
        s_hx[t] = acc;
    }
    for (int e = t; e < Kdim * Sdim; e += 64) {
        const int k = e / Sdim, ss = e - k * Sdim;
        const float* xj = input_data + ((size_t)b * Ndim + s_idx[k]) * Sdim;
        float acc = s_wb[ss];
        #pragma unroll
        for (int i = 0; i < Sdim; i++) acc += xj[i] * s_wW[i * Sdim + ss];
        s_whj[k][ss] = leaky(acc);
    }
    __syncthreads();

    for (int e = t; e < Kdim * Hdim; e += 64) {
        const int k = e / Hdim, d = e - k * Hdim;
        float acc = s_hx[d] + s_b1[d];
        #pragma unroll
        for (int s = 0; s < Sdim; s++) acc += s_whj[k][s] * s_A1[(Sdim + s) * Hdim + d];
        s_hid[k][d] = leaky(acc);
    }
    __syncthreads();

    for (int e = t; e < Kdim * Cdim; e += 64) {
        const int k = e / Cdim, c = e - k * Cdim;
        float acc = s_b2f[c];
        #pragma unroll
        for (int d = 0; d < Hdim; d++) acc += s_hid[k][d] * s_A2f[d * Cdim + c];
        s_am[k][c] = leaky(acc);
    }
    __syncthreads();

    if (t < Kdim) {
        float m = -1e30f;
        #pragma unroll
        for (int c = 0; c < Cdim; c++) m = fmaxf(m, s_am[t][c]);
        float ex[Cdim]; float sum = 0.f;
        #pragma unroll
        for (int c = 0; c < Cdim; c++) { ex[c] = expf(s_am[t][c] - m); sum += ex[c]; }
        const float inv = 1.f / sum;
        #pragma unroll
        for (int c = 0; c < Cdim; c++) s_am[t][c] = ex[c] * inv;
        float nn = 0.f;
        #pragma unroll
        for (int s = 0; s < Sdim; s++) nn += s_whj[t][s] * s_whj[t][s];
        const float invn = 1.f / (sqrtf(nn) + 1e-8f);
        #pragma unroll
        for (int s = 0; s < Sdim; s++) s_wtn[t][s] = s_whj[t][s] * invn;
    }
    __syncthreads();

    float* op = out + (size_t)bn * (Cdim * Sdim);
    for (int e = t; e < Cdim * Sdim; e += 64) {
        const int c = e / Sdim, ss = e - c * Sdim;
        float acc = 0.f;
        #pragma unroll
        for (int k = 0; k < Kdim; k++) acc += s_am[k][c] * s_whj[k][ss];
        op[e] = acc;
    }

    float cl = 0.f, ds = 0.f;
    for (int e = t; e < Kdim * Kdim; e += 64) {
        const int k = e / Kdim, l = e - k * Kdim;
        float d = 0.f;
        #pragma unroll
        for (int s = 0; s < Sdim; s++) d += s_wtn[k][s] * s_wtn[l][s];
        ds += d;
        if (k != l) {
            float p = 0.f;
            #pragma unroll
            for (int c = 0; c < Cdim; c++) p += s_am[k][c] * s_am[l][c];
            p = fminf(fmaxf(p, 1e-4f), 1.f - 1e-4f);
            const float lp = logf(p);
            cl += (d >= 0.5f) ? -lp : lp;
        }
    }
    float whl = (t < Sdim) ? s_whs[t] : 0.f;
    #pragma unroll
    for (int off = 32; off > 0; off >>= 1) {
        cl  += __shfl_down(cl,  off);
        ds  += __shfl_down(ds,  off);
        whl += __shfl_down(whl, off);
    }
    if (t == 0) {
        atomicAdd(&out[OUT_SCALARS + 0], cl  * (1.f / (float)NB));
        atomicAdd(&out[OUT_SCALARS + 1], ds  * (1.f / ((float)NB * Kdim * Kdim)));
        atomicAdd(&out[OUT_SCALARS + 2], whl * (1.f / ((float)NB * Sdim)));
    }
}

extern "C" void kernel_launch(void* const* d_in, const int* in_sizes, int n_in,
                              void* d_out, int out_size, void* d_ws, size_t ws_size,
                              hipStream_t stream) {
    (void)in_sizes; (void)n_in; (void)out_size;
    // 0=fushed_features(unused), 1=input_data, 2=w_W, 3=w_b, 4=a1_W, 5=a1_b,
    // 6=a2_W, 7=a2_b, 8=adj_mx_topk_index
    const float* input_data = (const float*)d_in[1];
    const float* w_W  = (const float*)d_in[2];
    const float* w_b  = (const float*)d_in[3];
    const float* a1_W = (const float*)d_in[4];
    const float* a1_b = (const float*)d_in[5];
    const float* a2_W = (const float*)d_in[6];
    const float* a2_b = (const float*)d_in[7];
    const int*   topk = (const int*)d_in[8];
    float* out = (float*)d_out;
    float* ws  = (float*)d_ws;

    if (ws_size >= (size_t)WS_BASE_FLOATS * sizeof(float)) {
        hipLaunchKernelGGL(node_kernel, dim3(NODE_BLOCKS), dim3(256), 0, stream,
                           input_data, w_W, w_b, a1_W, a1_b, ws);
        hipLaunchKernelGGL(mega_kernel, dim3(BN_BLOCKS), dim3(256), 0, stream,
                           topk, a2_W, a2_b, ws, out);
        hipLaunchKernelGGL(finalize, dim3(1), dim3(1024), 0, stream, ws, out);
    } else {
        hipLaunchKernelGGL(zero_scalars, dim3(1), dim3(64), 0, stream, out);
        hipLaunchKernelGGL(fused_kernel, dim3(NB), dim3(64), 0, stream,
                           input_data, w_W, w_b, a1_W, a1_b, a2_W, a2_b, topk, out);
    }
}